// Round 7
// baseline (362.229 us; speedup 1.0000x reference)
//
#include <hip/hip_runtime.h>
#include <hip/hip_bf16.h>

namespace {

constexpr int S_LEN  = 2048;
constexpr int DH     = 128;
constexpr int NG     = 16;     // global tokens
constexpr int HALF_W = 256;    // WINDOW/2
constexpr int TQ     = 64;     // q rows per main workgroup
constexpr int TK     = 32;     // keys per tile
constexpr int NT     = S_LEN / TK;  // 64
constexpr int BH     = 32;     // B*H
constexpr int NWG_MAIN = BH * (S_LEN / TQ);  // 1024
constexpr int PROW   = 40;     // padded plds row length in u16
constexpr int VPAD   = 140;    // prep LDS row pad (280 B: 8B-mult, 4-way worst)

typedef __attribute__((ext_vector_type(8))) short bf16x8;
typedef __attribute__((ext_vector_type(8))) unsigned short u16x8;
typedef __attribute__((ext_vector_type(4))) float f32x4;

__device__ __forceinline__ unsigned short bfhi(float x, float& rem) {
  unsigned b = __builtin_bit_cast(unsigned, x);
  unsigned short h = (unsigned short)(b >> 16);
  rem = x - __builtin_bit_cast(float, (unsigned)h << 16);
  return h;
}
__device__ __forceinline__ unsigned short bftr(float x) {
  return (unsigned short)(__builtin_bit_cast(unsigned, x) >> 16);
}
__device__ __forceinline__ unsigned short bfrn(float x) {
  return (unsigned short)((__builtin_bit_cast(unsigned, x) + 0x8000u) >> 16);
}

// ---------------- prepass: K fp32 -> Khi/Klo bf16 (same layout);
//                  V fp32 [s][d] -> VT bf16 [d][s]  ------------------------
template<bool DO_K>
__global__ __launch_bounds__(256)
void prep(const float* __restrict__ K, const float* __restrict__ V,
          unsigned short* __restrict__ VT,
          unsigned short* __restrict__ KH, unsigned short* __restrict__ KL)
{
  __shared__ unsigned short tile[64][VPAD];

  const int tid = threadIdx.x;
  const int bh  = (int)blockIdx.x >> 5;
  const int s0  = ((int)blockIdx.x & 31) * 64;
  const size_t base = (size_t)bh * S_LEN * DH;

  if (DO_K) {
    const float* Kb = K + base + (size_t)s0 * DH;
    unsigned short* KHb = KH + base + (size_t)s0 * DH;
    unsigned short* KLb = KL + base + (size_t)s0 * DH;
#pragma unroll
    for (int it = 0; it < 8; ++it) {
      const int e   = it * 256 + tid;      // float4 index, 2048 total
      const int row = e >> 5;
      const int dc  = (e & 31) * 4;
      float4 f = *(const float4*)(Kb + (size_t)row * DH + dc);
      ushort4 hv, lv; float r;
      hv.x = bfhi(f.x, r); lv.x = bftr(r);
      hv.y = bfhi(f.y, r); lv.y = bftr(r);
      hv.z = bfhi(f.z, r); lv.z = bftr(r);
      hv.w = bfhi(f.w, r); lv.w = bftr(r);
      *(ushort4*)(KHb + (size_t)row * DH + dc) = hv;
      *(ushort4*)(KLb + (size_t)row * DH + dc) = lv;
    }
  }

  // V: stage 64s x 128d tile to LDS (bf16), then write transposed
  const float* Vb = V + base + (size_t)s0 * DH;
#pragma unroll
  for (int it = 0; it < 8; ++it) {
    const int e   = it * 256 + tid;
    const int row = e >> 5;
    const int dc  = (e & 31) * 4;
    float4 f = *(const float4*)(Vb + (size_t)row * DH + dc);
    ushort4 u;
    u.x = bfrn(f.x); u.y = bfrn(f.y); u.z = bfrn(f.z); u.w = bfrn(f.w);
    *(ushort4*)&tile[row][dc] = u;
  }
  __syncthreads();

  unsigned short* VTb = VT + (size_t)bh * DH * S_LEN;
#pragma unroll
  for (int h = 0; h < 4; ++h) {
    const int chunk = h * 256 + tid;     // 1024 chunks of 16B
    const int drow  = chunk >> 3;        // 0..127
    const int sc8   = (chunk & 7) * 8;   // 0..56
    u16x8 u;
#pragma unroll
    for (int j = 0; j < 8; ++j) u[j] = tile[sc8 + j][drow];
    *(u16x8*)(VTb + (size_t)drow * S_LEN + s0 + sc8) = u;
  }
}

// ---------------- per-tile worker (swapped operands, no barriers) -----------
// S^T = mfma(A=K, B=Q): lane holds S[key=16n+g*4+r][qrow=lo16].
// O^T = mfma(A=V^T, B=P^T): lane holds O[d=16dt+g*4+r][qrow=lo16].
template<bool MASKED, bool USE_KP, bool USE_VT>
__device__ __forceinline__ void process_tile(
    int kt, int qb, int lo16, int g,
    const float* __restrict__ Kb,
    const unsigned short* __restrict__ KHb, const unsigned short* __restrict__ KLb,
    const unsigned short* __restrict__ VTb, const float* __restrict__ Vb,
    const bf16x8 (&qhi)[4], const bf16x8 (&qlo)[4],
    char* __restrict__ pw,
    float& mrow, float& lrow, f32x4 (&accO)[8])
{
  const int qrow = qb + lo16;
  const f32x4 zero4 = {0.f, 0.f, 0.f, 0.f};

  bf16x8 kh[2][4], kl[2][4];
  if (USE_KP) {
    // direct bf16 A-frag loads: 16 x 16B
#pragma unroll
    for (int n = 0; n < 2; ++n) {
      const size_t ro = (size_t)(kt + n * 16 + lo16) * DH + g * 8;
#pragma unroll
      for (int c = 0; c < 4; ++c) {
        kh[n][c] = *(const bf16x8*)(KHb + ro + c * 32);
        kl[n][c] = *(const bf16x8*)(KLb + ro + c * 32);
      }
    }
  } else {
    f32x4 kr[2][4][2];
#pragma unroll
    for (int n = 0; n < 2; ++n) {
      const float* kp = Kb + (size_t)(kt + n * 16 + lo16) * DH + g * 8;
#pragma unroll
      for (int c = 0; c < 4; ++c) {
        kr[n][c][0] = *(const f32x4*)(kp + c * 32);
        kr[n][c][1] = *(const f32x4*)(kp + c * 32 + 4);
      }
    }
#pragma unroll
    for (int n = 0; n < 2; ++n)
#pragma unroll
      for (int c = 0; c < 4; ++c)
#pragma unroll
        for (int j = 0; j < 8; ++j) {
          float x = (j < 4) ? kr[n][c][0][j] : kr[n][c][1][j - 4];
          float rr;
          kh[n][c][j] = (short)bfhi(x, rr);
          kl[n][c][j] = (short)bftr(rr);
        }
  }

  // ---- QK^T (hi/lo split, 3 mfma per 32-d chunk) ----
  f32x4 sc[2];
#pragma unroll
  for (int n = 0; n < 2; ++n) {
    f32x4 acc = zero4;
#pragma unroll
    for (int c = 0; c < 4; ++c) {
      acc = __builtin_amdgcn_mfma_f32_16x16x32_bf16(kl[n][c], qhi[c], acc, 0, 0, 0);
      acc = __builtin_amdgcn_mfma_f32_16x16x32_bf16(kh[n][c], qlo[c], acc, 0, 0, 0);
      acc = __builtin_amdgcn_mfma_f32_16x16x32_bf16(kh[n][c], qhi[c], acc, 0, 0, 0);
    }
    sc[n] = acc;
  }

  // ---- V loads issued here; consumed at PV (~softmax latency of cover) ----
  bf16x8 vb[8];
  if (USE_VT) {
    const unsigned short* vp = VTb + (size_t)lo16 * S_LEN + kt + g * 8;
#pragma unroll
    for (int dt = 0; dt < 8; ++dt)
      vb[dt] = *(const bf16x8*)(vp + (size_t)dt * 16 * S_LEN);
  } else {
#pragma unroll
    for (int dt = 0; dt < 8; ++dt) {
      const float* vp0 = Vb + (size_t)(kt + g * 8) * DH + dt * 16 + lo16;
      float t0[8];
#pragma unroll
      for (int j = 0; j < 8; ++j) t0[j] = vp0[(size_t)j * DH];
#pragma unroll
      for (int j = 0; j < 8; ++j) vb[dt][j] = (short)bfrn(t0[j]);
    }
  }

  // ---- mask ----
  if (MASKED) {
    const bool full = (kt >= qb + 15 - HALF_W) && (kt + TK - 1 <= qb + HALF_W);
    if (!full) {
#pragma unroll
      for (int n = 0; n < 2; ++n) {
#pragma unroll
        for (int r = 0; r < 4; ++r) {
          const int j = kt + n * 16 + g * 4 + r;
          const bool ok = ((unsigned)(j - qrow + HALF_W) <= 2u * HALF_W) || (j < NG);
          if (!ok) sc[n][r] = -3.0e4f;
        }
      }
    }
  }

  // ---- online softmax (q-row lane-local: 2 shuffles) ----
  float pmax = fmaxf(fmaxf(fmaxf(sc[0][0], sc[0][1]), fmaxf(sc[0][2], sc[0][3])),
                     fmaxf(fmaxf(sc[1][0], sc[1][1]), fmaxf(sc[1][2], sc[1][3])));
  pmax = fmaxf(pmax, __shfl_xor(pmax, 16, 64));
  pmax = fmaxf(pmax, __shfl_xor(pmax, 32, 64));
  if (!__all(pmax <= mrow + 8.0f)) {          // defer-max (T13)
    const float mnew = fmaxf(mrow, pmax);
    const float fr = __expf(mrow - mnew);
    lrow *= fr;
#pragma unroll
    for (int dt = 0; dt < 8; ++dt) accO[dt] *= fr;
    mrow = mnew;
  }
  float ps = 0.f;
#pragma unroll
  for (int n = 0; n < 2; ++n)
#pragma unroll
    for (int r = 0; r < 4; ++r) {
      sc[n][r] = __expf(sc[n][r] - mrow);
      ps += sc[n][r];
    }
  ps += __shfl_xor(ps, 16, 64);
  ps += __shfl_xor(ps, 32, 64);
  lrow += ps;

  // ---- P^T -> wave-private LDS -> B-frag (same-wave, no barrier) ----
#pragma unroll
  for (int n = 0; n < 2; ++n)
#pragma unroll
    for (int pr = 0; pr < 2; ++pr) {
      const unsigned pv = (unsigned)bfrn(sc[n][2 * pr]) |
                          ((unsigned)bfrn(sc[n][2 * pr + 1]) << 16);
      const int kpos = 16 * n + g * 4 + 2 * pr;
      const int slot = kpos >> 3;
      const int byte = lo16 * (PROW * 2) + ((slot ^ (lo16 & 3)) << 4) +
                       ((kpos & 7) << 1);
      *(unsigned*)(pw + byte) = pv;
    }
  bf16x8 pa;
  {
    const int byte = lo16 * (PROW * 2) + ((g ^ (lo16 & 3)) << 4);
    pa = *(const bf16x8*)(pw + byte);
  }

  // ---- P·V ----
#pragma unroll
  for (int dt = 0; dt < 8; ++dt)
    accO[dt] = __builtin_amdgcn_mfma_f32_16x16x32_bf16(vb[dt], pa, accO[dt], 0, 0, 0);
}

// ---------------- fused kernel: 1024 main blocks + 32 global-row blocks -----
template<bool USE_KP, bool USE_VT>
__global__ __launch_bounds__(256, 3)
void gla_fwd(const float* __restrict__ Q, const float* __restrict__ K,
             const float* __restrict__ V,
             const unsigned short* __restrict__ KH,
             const unsigned short* __restrict__ KL,
             const unsigned short* __restrict__ VT,
             float* __restrict__ O)
{
  __shared__ unsigned short plds[4 * 16 * PROW];   // 5 KB, wave-private slices
  __shared__ float macc[4][DH][16];                // 32 KB (global path only)
  __shared__ float mml[4][16][2];

  const int tid  = threadIdx.x;
  const int w    = tid >> 6;
  const int l    = tid & 63;
  const int lo16 = l & 15;
  const int g    = l >> 4;
  char* pw = (char*)(plds + w * (16 * PROW));

  const float scale = 0.08838834764831845f;  // 1/sqrt(128)
  const f32x4 zero4 = {0.f, 0.f, 0.f, 0.f};

  if (blockIdx.x < NWG_MAIN) {
    // =================== main path: window + global-cols ===================
    const int cpx = NWG_MAIN >> 3;
    const int bsw = ((int)blockIdx.x & 7) * cpx + ((int)blockIdx.x >> 3);
    const int bh  = bsw >> 5;
    const int i0  = (bsw & 31) * TQ;
    const int qb  = i0 + w * 16;
    if (qb == 0) return;          // rows 0..15 owned by the global path

    const size_t base = (size_t)bh * S_LEN * DH;
    const float* Qb = Q + base;
    const float* Kb = K + base;
    const float* Vb = V + base;
    const unsigned short* KHb = KH + base;
    const unsigned short* KLb = KL + base;
    const unsigned short* VTb = VT + base;
    float* Ob = O + base;

    bf16x8 qhi[4], qlo[4];
    {
      const float* qp = Qb + (size_t)(qb + lo16) * DH + g * 8;
#pragma unroll
      for (int c = 0; c < 4; ++c) {
        f32x4 a = *(const f32x4*)(qp + c * 32);
        f32x4 b = *(const f32x4*)(qp + c * 32 + 4);
#pragma unroll
        for (int j = 0; j < 8; ++j) {
          float x = ((j < 4) ? a[j] : b[j - 4]) * scale, rr;
          qhi[c][j] = (short)bfhi(x, rr);
          qlo[c][j] = (short)bftr(rr);
        }
      }
    }

    f32x4 accO[8];
#pragma unroll
    for (int dt = 0; dt < 8; ++dt) accO[dt] = zero4;
    float mrow = -1e30f, lrow = 0.f;

    int t_lo = (i0 - HALF_W) >> 5; if (t_lo < 0) t_lo = 0;
    int t_hi = (i0 + TQ - 1 + HALF_W) >> 5; if (t_hi > NT - 1) t_hi = NT - 1;
    const int tstart = (t_lo > 1) ? t_lo : 1;

    process_tile<true, USE_KP, USE_VT>(0, qb, lo16, g, Kb, KHb, KLb, VTb, Vb,
                                       qhi, qlo, pw, mrow, lrow, accO);
    for (int t = tstart; t <= t_hi; ++t)
      process_tile<true, USE_KP, USE_VT>(t * TK, qb, lo16, g, Kb, KHb, KLb,
                                         VTb, Vb, qhi, qlo, pw, mrow, lrow, accO);

    const float inv = 1.0f / lrow;
    float* op = Ob + (size_t)(qb + lo16) * DH;
#pragma unroll
    for (int dt = 0; dt < 8; ++dt) {
      f32x4 o = accO[dt] * inv;
      *(f32x4*)(op + dt * 16 + g * 4) = o;
    }
  } else {
    // =================== global-rows path: rows 0..15, all keys ============
    const int bh = (int)blockIdx.x - NWG_MAIN;
    const size_t base = (size_t)bh * S_LEN * DH;
    const float* Qb = Q + base;
    const float* Kb = K + base;
    const float* Vb = V + base;
    const unsigned short* KHb = KH + base;
    const unsigned short* KLb = KL + base;
    const unsigned short* VTb = VT + base;
    float* Ob = O + base;

    bf16x8 qhi[4], qlo[4];
    {
      const float* qp = Qb + (size_t)lo16 * DH + g * 8;
#pragma unroll
      for (int c = 0; c < 4; ++c) {
        f32x4 a = *(const f32x4*)(qp + c * 32);
        f32x4 b = *(const f32x4*)(qp + c * 32 + 4);
#pragma unroll
        for (int j = 0; j < 8; ++j) {
          float x = ((j < 4) ? a[j] : b[j - 4]) * scale, rr;
          qhi[c][j] = (short)bfhi(x, rr);
          qlo[c][j] = (short)bftr(rr);
        }
      }
    }

    f32x4 accO[8];
#pragma unroll
    for (int dt = 0; dt < 8; ++dt) accO[dt] = zero4;
    float mrow = -1e30f, lrow = 0.f;

    for (int i = 0; i < 16; ++i)
      process_tile<false, USE_KP, USE_VT>((w + 4 * i) * TK, 0, lo16, g, Kb,
                                          KHb, KLb, VTb, Vb, qhi, qlo, pw,
                                          mrow, lrow, accO);

#pragma unroll
    for (int dt = 0; dt < 8; ++dt)
#pragma unroll
      for (int r = 0; r < 4; ++r)
        macc[w][dt * 16 + g * 4 + r][lo16] = accO[dt][r];
    if (l < 16) { mml[w][l][0] = mrow; mml[w][l][1] = lrow; }
    __syncthreads();

    const int row = tid >> 4;          // 0..15
    const int d0  = (tid & 15) * 8;
    float mm[4], sw[4];
    float mstar = -1e30f;
#pragma unroll
    for (int w2 = 0; w2 < 4; ++w2) { mm[w2] = mml[w2][row][0]; mstar = fmaxf(mstar, mm[w2]); }
    float den = 0.f;
#pragma unroll
    for (int w2 = 0; w2 < 4; ++w2) { sw[w2] = __expf(mm[w2] - mstar); den += sw[w2] * mml[w2][row][1]; }
    const float inv = 1.0f / den;
    float outv[8];
#pragma unroll
    for (int dd = 0; dd < 8; ++dd) {
      float num = 0.f;
#pragma unroll
      for (int w2 = 0; w2 < 4; ++w2) num += sw[w2] * macc[w2][d0 + dd][row];
      outv[dd] = num * inv;
    }
    float* op = Ob + (size_t)row * DH + d0;
    f32x4 o0 = {outv[0], outv[1], outv[2], outv[3]};
    f32x4 o1 = {outv[4], outv[5], outv[6], outv[7]};
    *(f32x4*)op = o0;
    *(f32x4*)(op + 4) = o1;
  }
}

}  // namespace

extern "C" void kernel_launch(void* const* d_in, const int* in_sizes, int n_in,
                              void* d_out, int out_size, void* d_ws, size_t ws_size,
                              hipStream_t stream) {
  (void)in_sizes; (void)n_in; (void)out_size;
  const float* q = (const float*)d_in[0];
  const float* k = (const float*)d_in[1];
  const float* v = (const float*)d_in[2];
  float* o = (float*)d_out;

  const size_t seg = (size_t)BH * S_LEN * DH * sizeof(unsigned short); // 16 MB
  dim3 block(256);
  dim3 grid(NWG_MAIN + BH);   // 1024 main + 32 global-row blocks
  dim3 pgrid(BH * (S_LEN / 64));  // 1024 prep blocks

  if (ws_size >= 3 * seg) {
    unsigned short* vt = (unsigned short*)d_ws;
    unsigned short* kh = vt + seg / 2;       // seg bytes each, u16 elements
    unsigned short* kl = kh + seg / 2;
    prep<true><<<pgrid, block, 0, stream>>>(k, v, vt, kh, kl);
    gla_fwd<true, true><<<grid, block, 0, stream>>>(q, k, v, kh, kl, vt, o);
  } else if (ws_size >= seg) {
    unsigned short* vt = (unsigned short*)d_ws;
    prep<false><<<pgrid, block, 0, stream>>>(k, v, vt, nullptr, nullptr);
    gla_fwd<false, true><<<grid, block, 0, stream>>>(q, k, v, nullptr, nullptr, vt, o);
  } else {
    gla_fwd<false, false><<<grid, block, 0, stream>>>(q, k, v, nullptr, nullptr, nullptr, o);
  }
}

// Round 9
// 217.824 us; speedup vs baseline: 1.6629x; 1.6629x over previous
//
#include <hip/hip_runtime.h>
#include <hip/hip_bf16.h>

namespace {

constexpr int S_LEN  = 2048;
constexpr int DH     = 128;
constexpr int NG     = 16;     // global tokens
constexpr int HALF_W = 256;    // WINDOW/2
constexpr int TQ     = 64;     // q rows per main workgroup
constexpr int TK     = 32;     // keys per tile
constexpr int NT     = S_LEN / TK;  // 64
constexpr int BH     = 32;     // B*H
constexpr int NWG_MAIN = BH * (S_LEN / TQ);  // 1024
constexpr int PROW   = 40;     // padded plds row length in u16

typedef __attribute__((ext_vector_type(8))) short bf16x8;
typedef __attribute__((ext_vector_type(8))) unsigned short u16x8;
typedef __attribute__((ext_vector_type(4))) float f32x4;

__device__ __forceinline__ unsigned short bfhi(float x, float& rem) {
  unsigned b = __builtin_bit_cast(unsigned, x);
  unsigned short h = (unsigned short)(b >> 16);
  rem = x - __builtin_bit_cast(float, (unsigned)h << 16);
  return h;
}
__device__ __forceinline__ unsigned short bftr(float x) {
  return (unsigned short)(__builtin_bit_cast(unsigned, x) >> 16);
}
__device__ __forceinline__ unsigned short bfrn(float x) {
  return (unsigned short)((__builtin_bit_cast(unsigned, x) + 0x8000u) >> 16);
}

// ============ prepass: fragment-native repack ==============================
// KF (hi/lo): elem (((bh*NT+t)*8 + n*4+c)*64 + lane)*8 + j
//             = cvt(K[bh][t*32 + n*16 + (lane&15)][c*32 + (lane>>4)*8 + j])
// VF:         elem (((bh*NT+t)*8 + dt   )*64 + lane)*8 + j
//             = bfrn(V[bh][t*32 + (lane>>4)*8 + j][dt*16 + (lane&15)])
// Every main-loop load is then 64 lanes x 16 B contiguous (1 KB burst).
__global__ __launch_bounds__(256)
void prep(const float* __restrict__ K, const float* __restrict__ V,
          unsigned short* __restrict__ KFh, unsigned short* __restrict__ KFl,
          unsigned short* __restrict__ VF)
{
  const int tid = threadIdx.x;
  const int t   = (int)blockIdx.x & (NT - 1);
  const int bh  = (int)blockIdx.x >> 6;
  const size_t tile_in  = ((size_t)bh * S_LEN + (size_t)t * TK) * DH;
  const size_t tile_out = (size_t)(bh * NT + t) * 4096;   // u16 elems per tile

  // ---- K: coalesced float4 reads, 8B fragment writes ----
  {
    const float* kp = K + tile_in;
    unsigned short* oh = KFh + tile_out;
    unsigned short* ol = KFl + tile_out;
#pragma unroll
    for (int it = 0; it < 4; ++it) {
      const int f   = it * 1024 + tid * 4;   // flat fp32 idx in 32x128 tile
      float4 x = *(const float4*)(kp + f);
      const int r    = f >> 7;               // key row 0..31
      const int col  = f & 127;
      const int n    = r >> 4, lo16 = r & 15;
      const int c    = col >> 5, g = (col >> 3) & 3, j0 = col & 7; // j0 in {0,4}
      const int o    = ((n * 4 + c) * 64 + g * 16 + lo16) * 8 + j0;
      ushort4 hv, lv; float rr;
      hv.x = bfhi(x.x, rr); lv.x = bftr(rr);
      hv.y = bfhi(x.y, rr); lv.y = bftr(rr);
      hv.z = bfhi(x.z, rr); lv.z = bftr(rr);
      hv.w = bfhi(x.w, rr); lv.w = bftr(rr);
      *(ushort4*)(oh + o) = hv;
      *(ushort4*)(ol + o) = lv;
    }
  }

  // ---- V: column-gather reads (once per element), coalesced 16B writes ----
  {
    const float* vp = V + tile_in;
    unsigned short* ov = VF + tile_out;
#pragma unroll
    for (int i0 = 0; i0 < 2; ++i0) {
      const int idx  = i0 * 256 + tid;       // 0..511
      const int dt   = idx >> 6, lane = idx & 63;
      const int g    = lane >> 4, lo16 = lane & 15;
      float tv[8];
#pragma unroll
      for (int j = 0; j < 8; ++j)
        tv[j] = vp[(size_t)(8 * g + j) * DH + 16 * dt + lo16];
      u16x8 u;
#pragma unroll
      for (int j = 0; j < 8; ++j) u[j] = bfrn(tv[j]);
      *(u16x8*)(ov + (dt * 64 + lane) * 8) = u;
    }
  }
}

// ============ per-tile worker (swapped operands, no barriers) ==============
// S^T = mfma(A=K, B=Q): lane holds S[key=16n+g*4+r][qrow=lo16].
// O^T = mfma(A=V^T, B=P^T): lane holds O[d=16dt+g*4+r][qrow=lo16].
template<bool MASKED, bool USE_WS>
__device__ __forceinline__ void process_tile(
    int t, int qb, int l, int lo16, int g,
    const float* __restrict__ Kb, const float* __restrict__ Vb,
    const unsigned short* __restrict__ KFh,
    const unsigned short* __restrict__ KFl,
    const unsigned short* __restrict__ VF, size_t bhNT,
    const bf16x8 (&qhi)[4], const bf16x8 (&qlo)[4],
    char* __restrict__ pw,
    float& mrow, float& lrow, f32x4 (&accO)[8])
{
  const int kt   = t * TK;
  const int qrow = qb + lo16;
  const f32x4 zero4 = {0.f, 0.f, 0.f, 0.f};

  f32x4 sc[2];
  bf16x8 vb[8];

  if (USE_WS) {
    const size_t tile_out = (bhNT + (size_t)t) * 4096;
    // V loads first: 8 x 1KB coalesced bursts, consumed at PV
    const unsigned short* vf = VF + tile_out + l * 8;
#pragma unroll
    for (int dt = 0; dt < 8; ++dt)
      vb[dt] = *(const bf16x8*)(vf + dt * 512);
    // K per 16-key half: 8 x 1KB bursts each, short register life
    const unsigned short* kfh = KFh + tile_out + l * 8;
    const unsigned short* kfl = KFl + tile_out + l * 8;
#pragma unroll
    for (int n = 0; n < 2; ++n) {
      bf16x8 kh[4], kl[4];
#pragma unroll
      for (int c = 0; c < 4; ++c) {
        kh[c] = *(const bf16x8*)(kfh + (n * 4 + c) * 512);
        kl[c] = *(const bf16x8*)(kfl + (n * 4 + c) * 512);
      }
      f32x4 acc = zero4;
#pragma unroll
      for (int c = 0; c < 4; ++c) {
        acc = __builtin_amdgcn_mfma_f32_16x16x32_bf16(kl[c], qhi[c], acc, 0, 0, 0);
        acc = __builtin_amdgcn_mfma_f32_16x16x32_bf16(kh[c], qlo[c], acc, 0, 0, 0);
        acc = __builtin_amdgcn_mfma_f32_16x16x32_bf16(kh[c], qhi[c], acc, 0, 0, 0);
      }
      sc[n] = acc;
    }
  } else {
    // fallback: direct fp32 K + scalar V gather
#pragma unroll
    for (int n = 0; n < 2; ++n) {
      const float* kp = Kb + (size_t)(kt + n * 16 + lo16) * DH + g * 8;
      bf16x8 kh[4], kl[4];
#pragma unroll
      for (int c = 0; c < 4; ++c) {
        f32x4 a = *(const f32x4*)(kp + c * 32);
        f32x4 b = *(const f32x4*)(kp + c * 32 + 4);
#pragma unroll
        for (int j = 0; j < 8; ++j) {
          float x = (j < 4) ? a[j] : b[j - 4], rr;
          kh[c][j] = (short)bfhi(x, rr);
          kl[c][j] = (short)bftr(rr);
        }
      }
      f32x4 acc = zero4;
#pragma unroll
      for (int c = 0; c < 4; ++c) {
        acc = __builtin_amdgcn_mfma_f32_16x16x32_bf16(kl[c], qhi[c], acc, 0, 0, 0);
        acc = __builtin_amdgcn_mfma_f32_16x16x32_bf16(kh[c], qlo[c], acc, 0, 0, 0);
        acc = __builtin_amdgcn_mfma_f32_16x16x32_bf16(kh[c], qhi[c], acc, 0, 0, 0);
      }
      sc[n] = acc;
    }
#pragma unroll
    for (int dt = 0; dt < 8; ++dt) {
      const float* vp0 = Vb + (size_t)(kt + g * 8) * DH + dt * 16 + lo16;
      float t0[8];
#pragma unroll
      for (int j = 0; j < 8; ++j) t0[j] = vp0[(size_t)j * DH];
#pragma unroll
      for (int j = 0; j < 8; ++j) vb[dt][j] = (short)bfrn(t0[j]);
    }
  }

  // ---- mask ----
  if (MASKED) {
    const bool full = (kt >= qb + 15 - HALF_W) && (kt + TK - 1 <= qb + HALF_W);
    if (!full) {
#pragma unroll
      for (int n = 0; n < 2; ++n) {
#pragma unroll
        for (int r = 0; r < 4; ++r) {
          const int j = kt + n * 16 + g * 4 + r;
          const bool ok = ((unsigned)(j - qrow + HALF_W) <= 2u * HALF_W) || (j < NG);
          if (!ok) sc[n][r] = -3.0e4f;
        }
      }
    }
  }

  // ---- online softmax (q-row lane-local: 2 shuffles) ----
  float pmax = fmaxf(fmaxf(fmaxf(sc[0][0], sc[0][1]), fmaxf(sc[0][2], sc[0][3])),
                     fmaxf(fmaxf(sc[1][0], sc[1][1]), fmaxf(sc[1][2], sc[1][3])));
  pmax = fmaxf(pmax, __shfl_xor(pmax, 16, 64));
  pmax = fmaxf(pmax, __shfl_xor(pmax, 32, 64));
  if (!__all(pmax <= mrow + 8.0f)) {          // defer-max (T13)
    const float mnew = fmaxf(mrow, pmax);
    const float fr = __expf(mrow - mnew);
    lrow *= fr;
#pragma unroll
    for (int dt = 0; dt < 8; ++dt) accO[dt] *= fr;
    mrow = mnew;
  }
  float ps = 0.f;
#pragma unroll
  for (int n = 0; n < 2; ++n)
#pragma unroll
    for (int r = 0; r < 4; ++r) {
      sc[n][r] = __expf(sc[n][r] - mrow);
      ps += sc[n][r];
    }
  ps += __shfl_xor(ps, 16, 64);
  ps += __shfl_xor(ps, 32, 64);
  lrow += ps;

  // ---- P^T -> wave-private LDS -> B-frag (same-wave, no barrier) ----
#pragma unroll
  for (int n = 0; n < 2; ++n)
#pragma unroll
    for (int pr = 0; pr < 2; ++pr) {
      const unsigned pv = (unsigned)bfrn(sc[n][2 * pr]) |
                          ((unsigned)bfrn(sc[n][2 * pr + 1]) << 16);
      const int kpos = 16 * n + g * 4 + 2 * pr;
      const int slot = kpos >> 3;
      const int byte = lo16 * (PROW * 2) + ((slot ^ (lo16 & 3)) << 4) +
                       ((kpos & 7) << 1);
      *(unsigned*)(pw + byte) = pv;
    }
  bf16x8 pa;
  {
    const int byte = lo16 * (PROW * 2) + ((g ^ (lo16 & 3)) << 4);
    pa = *(const bf16x8*)(pw + byte);
  }

  // ---- P·V ----
#pragma unroll
  for (int dt = 0; dt < 8; ++dt)
    accO[dt] = __builtin_amdgcn_mfma_f32_16x16x32_bf16(vb[dt], pa, accO[dt], 0, 0, 0);
}

// ============ fused kernel: 1024 main + 32 global-row blocks ===============
template<bool USE_WS>
__global__ __launch_bounds__(256, 3)
void gla_fwd(const float* __restrict__ Q, const float* __restrict__ K,
             const float* __restrict__ V,
             const unsigned short* __restrict__ KFh,
             const unsigned short* __restrict__ KFl,
             const unsigned short* __restrict__ VF,
             float* __restrict__ O)
{
  __shared__ unsigned short plds[4 * 16 * PROW];   // 5 KB, wave-private slices
  __shared__ float macc[4][32][16];                // 8 KB (global path, chunked)
  __shared__ float mml[4][16][2];

  const int tid  = threadIdx.x;
  const int w    = tid >> 6;
  const int l    = tid & 63;
  const int lo16 = l & 15;
  const int g    = l >> 4;
  char* pw = (char*)(plds + w * (16 * PROW));

  const float scale = 0.08838834764831845f;  // 1/sqrt(128)
  const f32x4 zero4 = {0.f, 0.f, 0.f, 0.f};

  if (blockIdx.x < NWG_MAIN) {
    // =================== main path: window + global-cols ===================
    const int cpx = NWG_MAIN >> 3;
    const int bsw = ((int)blockIdx.x & 7) * cpx + ((int)blockIdx.x >> 3);
    const int bh  = bsw >> 5;
    const int i0  = (bsw & 31) * TQ;
    const int qb  = i0 + w * 16;
    if (qb == 0) return;          // rows 0..15 owned by the global path

    const size_t base = (size_t)bh * S_LEN * DH;
    const size_t bhNT = (size_t)bh * NT;
    const float* Qb = Q + base;
    const float* Kb = K + base;
    const float* Vb = V + base;
    float* Ob = O + base;

    bf16x8 qhi[4], qlo[4];
    {
      const float* qp = Qb + (size_t)(qb + lo16) * DH + g * 8;
#pragma unroll
      for (int c = 0; c < 4; ++c) {
        f32x4 a = *(const f32x4*)(qp + c * 32);
        f32x4 b = *(const f32x4*)(qp + c * 32 + 4);
#pragma unroll
        for (int j = 0; j < 8; ++j) {
          float x = ((j < 4) ? a[j] : b[j - 4]) * scale, rr;
          qhi[c][j] = (short)bfhi(x, rr);
          qlo[c][j] = (short)bftr(rr);
        }
      }
    }

    f32x4 accO[8];
#pragma unroll
    for (int dt = 0; dt < 8; ++dt) accO[dt] = zero4;
    float mrow = -1e30f, lrow = 0.f;

    int t_lo = (i0 - HALF_W) >> 5; if (t_lo < 0) t_lo = 0;
    int t_hi = (i0 + TQ - 1 + HALF_W) >> 5; if (t_hi > NT - 1) t_hi = NT - 1;
    const int tstart = (t_lo > 1) ? t_lo : 1;

    process_tile<true, USE_WS>(0, qb, l, lo16, g, Kb, Vb, KFh, KFl, VF, bhNT,
                               qhi, qlo, pw, mrow, lrow, accO);
    for (int t = tstart; t <= t_hi; ++t)
      process_tile<true, USE_WS>(t, qb, l, lo16, g, Kb, Vb, KFh, KFl, VF, bhNT,
                                 qhi, qlo, pw, mrow, lrow, accO);

    const float inv = 1.0f / lrow;
    float* op = Ob + (size_t)(qb + lo16) * DH;
#pragma unroll
    for (int dt = 0; dt < 8; ++dt) {
      f32x4 o = accO[dt] * inv;
      *(f32x4*)(op + dt * 16 + g * 4) = o;
    }
  } else {
    // =================== global-rows path: rows 0..15, all keys ============
    const int bh = (int)blockIdx.x - NWG_MAIN;
    const size_t base = (size_t)bh * S_LEN * DH;
    const size_t bhNT = (size_t)bh * NT;
    const float* Qb = Q + base;
    const float* Kb = K + base;
    const float* Vb = V + base;
    float* Ob = O + base;

    bf16x8 qhi[4], qlo[4];
    {
      const float* qp = Qb + (size_t)lo16 * DH + g * 8;
#pragma unroll
      for (int c = 0; c < 4; ++c) {
        f32x4 a = *(const f32x4*)(qp + c * 32);
        f32x4 b = *(const f32x4*)(qp + c * 32 + 4);
#pragma unroll
        for (int j = 0; j < 8; ++j) {
          float x = ((j < 4) ? a[j] : b[j - 4]) * scale, rr;
          qhi[c][j] = (short)bfhi(x, rr);
          qlo[c][j] = (short)bftr(rr);
        }
      }
    }

    f32x4 accO[8];
#pragma unroll
    for (int dt = 0; dt < 8; ++dt) accO[dt] = zero4;
    float mrow = -1e30f, lrow = 0.f;

    for (int i = 0; i < 16; ++i)
      process_tile<false, USE_WS>(w + 4 * i, 0, l, lo16, g, Kb, Vb, KFh, KFl,
                                  VF, bhNT, qhi, qlo, pw, mrow, lrow, accO);

    // ---- merge across the 4 waves, 32-d chunks (macc = 8 KB) ----
    if (l < 16) { mml[w][l][0] = mrow; mml[w][l][1] = lrow; }
    __syncthreads();

    const int row = tid & 15;
    float mm[4], sw[4];
    float mstar = -1e30f;
#pragma unroll
    for (int w2 = 0; w2 < 4; ++w2) { mm[w2] = mml[w2][row][0]; mstar = fmaxf(mstar, mm[w2]); }
    float den = 0.f;
#pragma unroll
    for (int w2 = 0; w2 < 4; ++w2) { sw[w2] = __expf(mm[w2] - mstar); den += sw[w2] * mml[w2][row][1]; }
    const float inv = 1.0f / den;

#pragma unroll
    for (int ch = 0; ch < 4; ++ch) {
#pragma unroll
      for (int dth = 0; dth < 2; ++dth) {
        const int dt = 2 * ch + dth;
#pragma unroll
        for (int r = 0; r < 4; ++r)
          macc[w][dth * 16 + g * 4 + r][lo16] = accO[dt][r];
      }
      __syncthreads();
#pragma unroll
      for (int dd = 0; dd < 2; ++dd) {
        const int dl = (tid >> 4) + 16 * dd;
        float num = 0.f;
#pragma unroll
        for (int w2 = 0; w2 < 4; ++w2) num += sw[w2] * macc[w2][dl][row];
        Ob[(size_t)row * DH + ch * 32 + dl] = num * inv;
      }
      __syncthreads();
    }
  }
}

}  // namespace

extern "C" void kernel_launch(void* const* d_in, const int* in_sizes, int n_in,
                              void* d_out, int out_size, void* d_ws, size_t ws_size,
                              hipStream_t stream) {
  (void)in_sizes; (void)n_in; (void)out_size;
  const float* q = (const float*)d_in[0];
  const float* k = (const float*)d_in[1];
  const float* v = (const float*)d_in[2];
  float* o = (float*)d_out;

  const size_t seg = (size_t)BH * S_LEN * DH * sizeof(unsigned short); // 16 MB
  dim3 block(256);
  dim3 grid(NWG_MAIN + BH);       // 1024 main + 32 global-row blocks
  dim3 pgrid(BH * NT);            // 2048 prep blocks

  if (ws_size >= 3 * seg) {
    unsigned short* kfh = (unsigned short*)d_ws;
    unsigned short* kfl = kfh + seg / 2;     // seg bytes each (u16 elems)
    unsigned short* vf  = kfl + seg / 2;
    prep<<<pgrid, block, 0, stream>>>(k, v, kfh, kfl, vf);
    gla_fwd<true><<<grid, block, 0, stream>>>(q, k, v, kfh, kfl, vf, o);
  } else {
    gla_fwd<false><<<grid, block, 0, stream>>>(q, k, v, nullptr, nullptr, nullptr, o);
  }
}

// Round 10
// 216.524 us; speedup vs baseline: 1.6729x; 1.0060x over previous
//
#include <hip/hip_runtime.h>
#include <hip/hip_bf16.h>

namespace {

constexpr int S_LEN  = 2048;
constexpr int DH     = 128;
constexpr int NG     = 16;     // global tokens
constexpr int HALF_W = 256;    // WINDOW/2
constexpr int TQ     = 64;     // q rows per main workgroup
constexpr int TK     = 32;     // keys per tile
constexpr int NT     = S_LEN / TK;  // 64
constexpr int BH     = 32;     // B*H
constexpr int NWG_MAIN = BH * (S_LEN / TQ);  // 1024
constexpr int PROW   = 40;     // padded plds row length in u16

typedef __attribute__((ext_vector_type(8))) short bf16x8;
typedef __attribute__((ext_vector_type(8))) unsigned short u16x8;
typedef __attribute__((ext_vector_type(4))) float f32x4;

__device__ __forceinline__ unsigned short bfhi(float x, float& rem) {
  unsigned b = __builtin_bit_cast(unsigned, x);
  unsigned short h = (unsigned short)(b >> 16);
  rem = x - __builtin_bit_cast(float, (unsigned)h << 16);
  return h;
}
__device__ __forceinline__ unsigned short bftr(float x) {
  return (unsigned short)(__builtin_bit_cast(unsigned, x) >> 16);
}
__device__ __forceinline__ unsigned short bfrn(float x) {
  return (unsigned short)((__builtin_bit_cast(unsigned, x) + 0x8000u) >> 16);
}

// ============ prepass v2: LDS-staged fragment repack =======================
// Same output layouts as R9 (verified):
// KF (hi/lo): elem (((bh*NT+t)*8 + n*4+c)*64 + lane)*8 + j
//             = cvt(K[bh][t*32 + n*16 + (lane&15)][c*32 + (lane>>4)*8 + j])
// VF:         elem (((bh*NT+t)*8 + dt   )*64 + lane)*8 + j
//             = bfrn(V[bh][t*32 + (lane>>4)*8 + j][dt*16 + (lane&15)])
// v2: global reads fully coalesced float4; fragment scatter goes to LDS;
// global writes are linear 16B bursts (1 KB/wave). Scatter cost stays in LDS.
__global__ __launch_bounds__(256)
void prep(const float* __restrict__ K, const float* __restrict__ V,
          unsigned short* __restrict__ KFh, unsigned short* __restrict__ KFl,
          unsigned short* __restrict__ VF)
{
  __shared__ __align__(16) unsigned short lkh[4096];   // 8 KB
  __shared__ __align__(16) unsigned short lkl[4096];   // 8 KB
  __shared__ __align__(16) unsigned short lvf[4096];   // 8 KB

  const int tid = threadIdx.x;
  const int t   = (int)blockIdx.x & (NT - 1);
  const int bh  = (int)blockIdx.x >> 6;
  const size_t tile_in  = ((size_t)bh * S_LEN + (size_t)t * TK) * DH;
  const size_t tile_out = (size_t)(bh * NT + t) * 4096;   // u16 elems per tile

  // ---- phase A: K coalesced float4 read -> hi/lo -> LDS fragment scatter --
  {
    const float* kp = K + tile_in;
#pragma unroll
    for (int it = 0; it < 4; ++it) {
      const int f   = it * 1024 + tid * 4;   // flat fp32 idx in 32x128 tile
      float4 x = *(const float4*)(kp + f);
      const int r    = f >> 7;               // key row 0..31
      const int col  = f & 127;
      const int n    = r >> 4, lo16 = r & 15;
      const int c    = col >> 5, g = (col >> 3) & 3, j0 = col & 7; // j0 in {0,4}
      const int o    = ((n * 4 + c) * 64 + g * 16 + lo16) * 8 + j0;
      ushort4 hv, lv; float rr;
      hv.x = bfhi(x.x, rr); lv.x = bftr(rr);
      hv.y = bfhi(x.y, rr); lv.y = bftr(rr);
      hv.z = bfhi(x.z, rr); lv.z = bftr(rr);
      hv.w = bfhi(x.w, rr); lv.w = bftr(rr);
      *(ushort4*)&lkh[o] = hv;
      *(ushort4*)&lkl[o] = lv;
    }
  }

  // ---- phase B: V coalesced float4 read -> LDS transpose scatter ----------
  {
    const float* vp = V + tile_in;
#pragma unroll
    for (int it = 0; it < 4; ++it) {
      const int f   = it * 1024 + tid * 4;
      float4 x = *(const float4*)(vp + f);
      const int row = f >> 7;                // v row 0..31
      const int col = f & 127;               // multiple of 4, col&15 <= 12
      const int g   = row >> 3, j = row & 7, dt = col >> 4;
      const int e0  = dt * 512 + g * 128 + (col & 15) * 8 + j;
      lvf[e0]      = bfrn(x.x);
      lvf[e0 + 8]  = bfrn(x.y);
      lvf[e0 + 16] = bfrn(x.z);
      lvf[e0 + 24] = bfrn(x.w);
    }
  }
  __syncthreads();

  // ---- phase C: linear LDS -> global, 16B per thread per array ------------
#pragma unroll
  for (int p = 0; p < 2; ++p) {
    const int e = (p * 256 + tid) * 8;
    *(u16x8*)(KFh + tile_out + e) = *(const u16x8*)&lkh[e];
    *(u16x8*)(KFl + tile_out + e) = *(const u16x8*)&lkl[e];
    *(u16x8*)(VF  + tile_out + e) = *(const u16x8*)&lvf[e];
  }
}

// ============ per-tile worker (swapped operands, no barriers) ==============
// S^T = mfma(A=K, B=Q): lane holds S[key=16n+g*4+r][qrow=lo16].
// O^T = mfma(A=V^T, B=P^T): lane holds O[d=16dt+g*4+r][qrow=lo16].
template<bool MASKED, bool USE_WS>
__device__ __forceinline__ void process_tile(
    int t, int qb, int l, int lo16, int g,
    const float* __restrict__ Kb, const float* __restrict__ Vb,
    const unsigned short* __restrict__ KFh,
    const unsigned short* __restrict__ KFl,
    const unsigned short* __restrict__ VF, size_t bhNT,
    const bf16x8 (&qhi)[4], const bf16x8 (&qlo)[4],
    char* __restrict__ pw,
    float& mrow, float& lrow, f32x4 (&accO)[8])
{
  const int kt   = t * TK;
  const int qrow = qb + lo16;
  const f32x4 zero4 = {0.f, 0.f, 0.f, 0.f};

  f32x4 sc[2];
  bf16x8 vb[8];

  if (USE_WS) {
    const size_t tile_out = (bhNT + (size_t)t) * 4096;
    // V loads first: 8 x 1KB coalesced bursts, consumed at PV
    const unsigned short* vf = VF + tile_out + l * 8;
#pragma unroll
    for (int dt = 0; dt < 8; ++dt)
      vb[dt] = *(const bf16x8*)(vf + dt * 512);
    // K per 16-key half: 8 x 1KB bursts each, short register life
    const unsigned short* kfh = KFh + tile_out + l * 8;
    const unsigned short* kfl = KFl + tile_out + l * 8;
#pragma unroll
    for (int n = 0; n < 2; ++n) {
      bf16x8 kh[4], kl[4];
#pragma unroll
      for (int c = 0; c < 4; ++c) {
        kh[c] = *(const bf16x8*)(kfh + (n * 4 + c) * 512);
        kl[c] = *(const bf16x8*)(kfl + (n * 4 + c) * 512);
      }
      f32x4 acc = zero4;
#pragma unroll
      for (int c = 0; c < 4; ++c) {
        acc = __builtin_amdgcn_mfma_f32_16x16x32_bf16(kl[c], qhi[c], acc, 0, 0, 0);
        acc = __builtin_amdgcn_mfma_f32_16x16x32_bf16(kh[c], qlo[c], acc, 0, 0, 0);
        acc = __builtin_amdgcn_mfma_f32_16x16x32_bf16(kh[c], qhi[c], acc, 0, 0, 0);
      }
      sc[n] = acc;
    }
  } else {
    // fallback: direct fp32 K + scalar V gather
#pragma unroll
    for (int n = 0; n < 2; ++n) {
      const float* kp = Kb + (size_t)(kt + n * 16 + lo16) * DH + g * 8;
      bf16x8 kh[4], kl[4];
#pragma unroll
      for (int c = 0; c < 4; ++c) {
        f32x4 a = *(const f32x4*)(kp + c * 32);
        f32x4 b = *(const f32x4*)(kp + c * 32 + 4);
#pragma unroll
        for (int j = 0; j < 8; ++j) {
          float x = (j < 4) ? a[j] : b[j - 4], rr;
          kh[c][j] = (short)bfhi(x, rr);
          kl[c][j] = (short)bftr(rr);
        }
      }
      f32x4 acc = zero4;
#pragma unroll
      for (int c = 0; c < 4; ++c) {
        acc = __builtin_amdgcn_mfma_f32_16x16x32_bf16(kl[c], qhi[c], acc, 0, 0, 0);
        acc = __builtin_amdgcn_mfma_f32_16x16x32_bf16(kh[c], qlo[c], acc, 0, 0, 0);
        acc = __builtin_amdgcn_mfma_f32_16x16x32_bf16(kh[c], qhi[c], acc, 0, 0, 0);
      }
      sc[n] = acc;
    }
#pragma unroll
    for (int dt = 0; dt < 8; ++dt) {
      const float* vp0 = Vb + (size_t)(kt + g * 8) * DH + dt * 16 + lo16;
      float t0[8];
#pragma unroll
      for (int j = 0; j < 8; ++j) t0[j] = vp0[(size_t)j * DH];
#pragma unroll
      for (int j = 0; j < 8; ++j) vb[dt][j] = (short)bfrn(t0[j]);
    }
  }

  // ---- mask ----
  if (MASKED) {
    const bool full = (kt >= qb + 15 - HALF_W) && (kt + TK - 1 <= qb + HALF_W);
    if (!full) {
#pragma unroll
      for (int n = 0; n < 2; ++n) {
#pragma unroll
        for (int r = 0; r < 4; ++r) {
          const int j = kt + n * 16 + g * 4 + r;
          const bool ok = ((unsigned)(j - qrow + HALF_W) <= 2u * HALF_W) || (j < NG);
          if (!ok) sc[n][r] = -3.0e4f;
        }
      }
    }
  }

  // ---- online softmax (q-row lane-local: 2 shuffles) ----
  float pmax = fmaxf(fmaxf(fmaxf(sc[0][0], sc[0][1]), fmaxf(sc[0][2], sc[0][3])),
                     fmaxf(fmaxf(sc[1][0], sc[1][1]), fmaxf(sc[1][2], sc[1][3])));
  pmax = fmaxf(pmax, __shfl_xor(pmax, 16, 64));
  pmax = fmaxf(pmax, __shfl_xor(pmax, 32, 64));
  if (!__all(pmax <= mrow + 8.0f)) {          // defer-max (T13)
    const float mnew = fmaxf(mrow, pmax);
    const float fr = __expf(mrow - mnew);
    lrow *= fr;
#pragma unroll
    for (int dt = 0; dt < 8; ++dt) accO[dt] *= fr;
    mrow = mnew;
  }
  float ps = 0.f;
#pragma unroll
  for (int n = 0; n < 2; ++n)
#pragma unroll
    for (int r = 0; r < 4; ++r) {
      sc[n][r] = __expf(sc[n][r] - mrow);
      ps += sc[n][r];
    }
  ps += __shfl_xor(ps, 16, 64);
  ps += __shfl_xor(ps, 32, 64);
  lrow += ps;

  // ---- P^T -> wave-private LDS -> B-frag (same-wave, no barrier) ----
#pragma unroll
  for (int n = 0; n < 2; ++n)
#pragma unroll
    for (int pr = 0; pr < 2; ++pr) {
      const unsigned pv = (unsigned)bfrn(sc[n][2 * pr]) |
                          ((unsigned)bfrn(sc[n][2 * pr + 1]) << 16);
      const int kpos = 16 * n + g * 4 + 2 * pr;
      const int slot = kpos >> 3;
      const int byte = lo16 * (PROW * 2) + ((slot ^ (lo16 & 3)) << 4) +
                       ((kpos & 7) << 1);
      *(unsigned*)(pw + byte) = pv;
    }
  bf16x8 pa;
  {
    const int byte = lo16 * (PROW * 2) + ((g ^ (lo16 & 3)) << 4);
    pa = *(const bf16x8*)(pw + byte);
  }

  // ---- P·V ----
#pragma unroll
  for (int dt = 0; dt < 8; ++dt)
    accO[dt] = __builtin_amdgcn_mfma_f32_16x16x32_bf16(vb[dt], pa, accO[dt], 0, 0, 0);
}

// ============ fused kernel: 1024 main + 32 global-row blocks ===============
template<bool USE_WS>
__global__ __launch_bounds__(256, 3)
void gla_fwd(const float* __restrict__ Q, const float* __restrict__ K,
             const float* __restrict__ V,
             const unsigned short* __restrict__ KFh,
             const unsigned short* __restrict__ KFl,
             const unsigned short* __restrict__ VF,
             float* __restrict__ O)
{
  __shared__ unsigned short plds[4 * 16 * PROW];   // 5 KB, wave-private slices
  __shared__ float macc[4][32][16];                // 8 KB (global path, chunked)
  __shared__ float mml[4][16][2];

  const int tid  = threadIdx.x;
  const int w    = tid >> 6;
  const int l    = tid & 63;
  const int lo16 = l & 15;
  const int g    = l >> 4;
  char* pw = (char*)(plds + w * (16 * PROW));

  const float scale = 0.08838834764831845f;  // 1/sqrt(128)
  const f32x4 zero4 = {0.f, 0.f, 0.f, 0.f};

  if (blockIdx.x < NWG_MAIN) {
    // =================== main path: window + global-cols ===================
    const int cpx = NWG_MAIN >> 3;
    const int bsw = ((int)blockIdx.x & 7) * cpx + ((int)blockIdx.x >> 3);
    const int bh  = bsw >> 5;
    const int i0  = (bsw & 31) * TQ;
    const int qb  = i0 + w * 16;
    if (qb == 0) return;          // rows 0..15 owned by the global path

    const size_t base = (size_t)bh * S_LEN * DH;
    const size_t bhNT = (size_t)bh * NT;
    const float* Qb = Q + base;
    const float* Kb = K + base;
    const float* Vb = V + base;
    float* Ob = O + base;

    bf16x8 qhi[4], qlo[4];
    {
      const float* qp = Qb + (size_t)(qb + lo16) * DH + g * 8;
#pragma unroll
      for (int c = 0; c < 4; ++c) {
        f32x4 a = *(const f32x4*)(qp + c * 32);
        f32x4 b = *(const f32x4*)(qp + c * 32 + 4);
#pragma unroll
        for (int j = 0; j < 8; ++j) {
          float x = ((j < 4) ? a[j] : b[j - 4]) * scale, rr;
          qhi[c][j] = (short)bfhi(x, rr);
          qlo[c][j] = (short)bftr(rr);
        }
      }
    }

    f32x4 accO[8];
#pragma unroll
    for (int dt = 0; dt < 8; ++dt) accO[dt] = zero4;
    float mrow = -1e30f, lrow = 0.f;

    int t_lo = (i0 - HALF_W) >> 5; if (t_lo < 0) t_lo = 0;
    int t_hi = (i0 + TQ - 1 + HALF_W) >> 5; if (t_hi > NT - 1) t_hi = NT - 1;
    const int tstart = (t_lo > 1) ? t_lo : 1;

    process_tile<true, USE_WS>(0, qb, l, lo16, g, Kb, Vb, KFh, KFl, VF, bhNT,
                               qhi, qlo, pw, mrow, lrow, accO);
    for (int t = tstart; t <= t_hi; ++t)
      process_tile<true, USE_WS>(t, qb, l, lo16, g, Kb, Vb, KFh, KFl, VF, bhNT,
                                 qhi, qlo, pw, mrow, lrow, accO);

    const float inv = 1.0f / lrow;
    float* op = Ob + (size_t)(qb + lo16) * DH;
#pragma unroll
    for (int dt = 0; dt < 8; ++dt) {
      f32x4 o = accO[dt] * inv;
      *(f32x4*)(op + dt * 16 + g * 4) = o;
    }
  } else {
    // =================== global-rows path: rows 0..15, all keys ============
    const int bh = (int)blockIdx.x - NWG_MAIN;
    const size_t base = (size_t)bh * S_LEN * DH;
    const size_t bhNT = (size_t)bh * NT;
    const float* Qb = Q + base;
    const float* Kb = K + base;
    const float* Vb = V + base;
    float* Ob = O + base;

    bf16x8 qhi[4], qlo[4];
    {
      const float* qp = Qb + (size_t)lo16 * DH + g * 8;
#pragma unroll
      for (int c = 0; c < 4; ++c) {
        f32x4 a = *(const f32x4*)(qp + c * 32);
        f32x4 b = *(const f32x4*)(qp + c * 32 + 4);
#pragma unroll
        for (int j = 0; j < 8; ++j) {
          float x = ((j < 4) ? a[j] : b[j - 4]) * scale, rr;
          qhi[c][j] = (short)bfhi(x, rr);
          qlo[c][j] = (short)bftr(rr);
        }
      }
    }

    f32x4 accO[8];
#pragma unroll
    for (int dt = 0; dt < 8; ++dt) accO[dt] = zero4;
    float mrow = -1e30f, lrow = 0.f;

    for (int i = 0; i < 16; ++i)
      process_tile<false, USE_WS>(w + 4 * i, 0, l, lo16, g, Kb, Vb, KFh, KFl,
                                  VF, bhNT, qhi, qlo, pw, mrow, lrow, accO);

    // ---- merge across the 4 waves, 32-d chunks (macc = 8 KB) ----
    if (l < 16) { mml[w][l][0] = mrow; mml[w][l][1] = lrow; }
    __syncthreads();

    const int row = tid & 15;
    float mm[4], sw[4];
    float mstar = -1e30f;
#pragma unroll
    for (int w2 = 0; w2 < 4; ++w2) { mm[w2] = mml[w2][row][0]; mstar = fmaxf(mstar, mm[w2]); }
    float den = 0.f;
#pragma unroll
    for (int w2 = 0; w2 < 4; ++w2) { sw[w2] = __expf(mm[w2] - mstar); den += sw[w2] * mml[w2][row][1]; }
    const float inv = 1.0f / den;

#pragma unroll
    for (int ch = 0; ch < 4; ++ch) {
#pragma unroll
      for (int dth = 0; dth < 2; ++dth) {
        const int dt = 2 * ch + dth;
#pragma unroll
        for (int r = 0; r < 4; ++r)
          macc[w][dth * 16 + g * 4 + r][lo16] = accO[dt][r];
      }
      __syncthreads();
#pragma unroll
      for (int dd = 0; dd < 2; ++dd) {
        const int dl = (tid >> 4) + 16 * dd;
        float num = 0.f;
#pragma unroll
        for (int w2 = 0; w2 < 4; ++w2) num += sw[w2] * macc[w2][dl][row];
        Ob[(size_t)row * DH + ch * 32 + dl] = num * inv;
      }
      __syncthreads();
    }
  }
}

}  // namespace

extern "C" void kernel_launch(void* const* d_in, const int* in_sizes, int n_in,
                              void* d_out, int out_size, void* d_ws, size_t ws_size,
                              hipStream_t stream) {
  (void)in_sizes; (void)n_in; (void)out_size;
  const float* q = (const float*)d_in[0];
  const float* k = (const float*)d_in[1];
  const float* v = (const float*)d_in[2];
  float* o = (float*)d_out;

  const size_t seg = (size_t)BH * S_LEN * DH * sizeof(unsigned short); // 16 MB
  dim3 block(256);
  dim3 grid(NWG_MAIN + BH);       // 1024 main + 32 global-row blocks
  dim3 pgrid(BH * NT);            // 2048 prep blocks

  if (ws_size >= 3 * seg) {
    unsigned short* kfh = (unsigned short*)d_ws;
    unsigned short* kfl = kfh + seg / 2;     // seg bytes each (u16 elems)
    unsigned short* vf  = kfl + seg / 2;
    prep<<<pgrid, block, 0, stream>>>(k, v, kfh, kfl, vf);
    gla_fwd<true><<<grid, block, 0, stream>>>(q, k, v, kfh, kfl, vf, o);
  } else {
    gla_fwd<false><<<grid, block, 0, stream>>>(q, k, v, nullptr, nullptr, nullptr, o);
  }
}